// Round 1
// baseline (1034.156 us; speedup 1.0000x reference)
//
#include <hip/hip_runtime.h>
#include <hip/hip_bf16.h>

typedef __bf16 bf16;
typedef __bf16 bf16x8 __attribute__((ext_vector_type(8)));
typedef float f32x4 __attribute__((ext_vector_type(4)));

#define DEVI static __device__ __forceinline__

static constexpr int Bn = 4, Cc = 192, Hh = 256, Wd = 256;
static constexpr int NHd = 6, HD = 32;
static constexpr int OVp = 4;
static constexpr int Mtot = Bn * Hh * Wd;          // 262144 pixels
static constexpr float EPSv = 1e-5f;

DEVI f32x4 mfma16(bf16x8 a, bf16x8 b, f32x4 c) {
    return __builtin_amdgcn_mfma_f32_16x16x32_bf16(a, b, c, 0, 0, 0);
}

// ---------------------------------------------------------------- K0: weights
__global__ __launch_bounds__(256) void k_prep(const float* Wq, const float* Wkv,
                                              const float* Wo, bf16* WqT,
                                              bf16* WkvT, bf16* WoT) {
    int idx = blockIdx.x * 256 + threadIdx.x;
    if (idx < 192 * 192) { int k = idx / 192, n = idx % 192; WqT[n * 192 + k] = (bf16)Wq[idx]; }
    if (idx < 192 * 384) { int k = idx / 384, n = idx % 384; WkvT[n * 192 + k] = (bf16)Wkv[idx]; }
    if (idx < 192 * 192) { int k = idx / 192, n = idx % 192; WoT[n * 192 + k] = (bf16)Wo[idx]; }
}

// ---------------------------------------------------------------- K1: layernorm
// BCHW f32 -> BHWC bf16. One block per (b,h) row, one thread per pixel (w).
__global__ __launch_bounds__(256) void k_ln(const float* __restrict__ x,
                                            const float* __restrict__ gamma,
                                            const float* __restrict__ beta,
                                            bf16* __restrict__ ln) {
    int bh = blockIdx.x;                 // b*H + h
    int w = threadIdx.x;
    __shared__ float sg[Cc], sb[Cc];
    if (threadIdx.x < Cc) { sg[threadIdx.x] = gamma[threadIdx.x]; sb[threadIdx.x] = beta[threadIdx.x]; }
    __syncthreads();
    const float* xp = x + (size_t)bh * Wd + w
                      + (size_t)(bh / Hh) * (Cc - 1) * Hh * Wd; // base for c=0
    // xp addressing: x[((b*C + c)*H + h)*W + w] = x[b*C*H*W + c*H*W + h*W + w]
    const size_t cs = (size_t)Hh * Wd;
    float s = 0.f, s2 = 0.f;
#pragma unroll 8
    for (int c = 0; c < Cc; ++c) { float v = xp[c * cs]; s += v; s2 += v * v; }
    float mu = s * (1.f / Cc);
    float var = s2 * (1.f / Cc) - mu * mu;
    float rs = rsqrtf(var + EPSv);
    bf16* lr = ln + ((size_t)bh * Wd + w) * Cc;
    for (int c0 = Cc - 8; c0 >= 0; c0 -= 8) {   // descending: better L2 reuse of pass-1 lines
        bf16x8 o;
#pragma unroll
        for (int j = 0; j < 8; ++j) {
            int c = c0 + j;
            float v = xp[c * cs];
            o[j] = (bf16)((v - mu) * rs * sg[c] + sb[c]);
        }
        *(bf16x8*)(lr + c0) = o;
    }
}

// ---------------------------------------------------------------- K2/K3: projections
// Out[M, NOUT] = A[M,192] @ WT(row n holds K) + bias. 64 rows / block, 4 waves split N.
template <int NOUT>
__global__ __launch_bounds__(256) void k_gemm(const bf16* __restrict__ A,
                                              const bf16* __restrict__ WT,
                                              const float* __restrict__ bias,
                                              bf16* __restrict__ Out) {
    constexpr int NT = NOUT / 64;        // n-tiles per wave (192->3, 384->6)
    int row0 = blockIdx.x * 64;
    int tid = threadIdx.x, wave = tid >> 6, lane = tid & 63;
    int l15 = lane & 15, g = lane >> 4;
    int nb = wave * (NOUT / 4);
    f32x4 acc[4][NT] = {};
    const bf16* Arow[4];
#pragma unroll
    for (int mt = 0; mt < 4; ++mt) Arow[mt] = A + (size_t)(row0 + mt * 16 + l15) * Cc + g * 8;
    const bf16* Wrow[NT];
#pragma unroll
    for (int nt = 0; nt < NT; ++nt) Wrow[nt] = WT + (size_t)(nb + nt * 16 + l15) * Cc + g * 8;
#pragma unroll
    for (int kk = 0; kk < 6; ++kk) {
        bf16x8 a[4];
#pragma unroll
        for (int mt = 0; mt < 4; ++mt) a[mt] = *(const bf16x8*)(Arow[mt] + kk * 32);
#pragma unroll
        for (int nt = 0; nt < NT; ++nt) {
            bf16x8 bb = *(const bf16x8*)(Wrow[nt] + kk * 32);
#pragma unroll
            for (int mt = 0; mt < 4; ++mt) acc[mt][nt] = mfma16(a[mt], bb, acc[mt][nt]);
        }
    }
#pragma unroll
    for (int nt = 0; nt < NT; ++nt) {
        float bval = bias[nb + nt * 16 + l15];
#pragma unroll
        for (int mt = 0; mt < 4; ++mt)
#pragma unroll
            for (int r = 0; r < 4; ++r) {
                int row = row0 + mt * 16 + g * 4 + r;
                Out[(size_t)row * NOUT + nb + nt * 16 + l15] = (bf16)(acc[mt][nt][r] + bval);
            }
    }
}

// ---------------------------------------------------------------- K4: attention
// One block per (window, head). 4 waves x 16 q-rows. kv = 256 overlapping rows.
__global__ __launch_bounds__(256) void k_attn(const bf16* __restrict__ Q,
                                              const bf16* __restrict__ KV,
                                              const float* __restrict__ bkv,
                                              bf16* __restrict__ O) {
    int win = blockIdx.x / NHd, head = blockIdx.x % NHd;
    int b = win >> 10, wloc = win & 1023;
    int h0 = (wloc >> 5) * 8, w0 = (wloc & 31) * 8;
    int tid = threadIdx.x, wave = tid >> 6, lane = tid & 63;
    int l15 = lane & 15, g = lane >> 4;

    __shared__ __align__(16) bf16 VT[32 * 264];   // V^T: [d][kv], padded stride
    __shared__ __align__(16) bf16 P[64 * 264];    // probs: [qrow][kv], padded stride

    // ---- stage V^T (one kv row per thread)
    {
        int r = tid;
        int ph = h0 - OVp + (r >> 4), pw = w0 - OVp + (r & 15);
        bool ok = ((unsigned)ph < (unsigned)Hh) && ((unsigned)pw < (unsigned)Wd);
        size_t pix = ok ? ((size_t)(b * Hh + ph) * Wd + pw) : 0;
        const bf16* vr = KV + pix * (2 * Cc) + Cc + head * HD;
        const float* vb = bkv + Cc + head * HD;
#pragma unroll
        for (int d0 = 0; d0 < 32; d0 += 8) {
            bf16x8 v8 = *(const bf16x8*)(vr + d0);
#pragma unroll
            for (int j = 0; j < 8; ++j) {
                bf16 val = ok ? v8[j] : (bf16)vb[d0 + j];
                VT[(d0 + j) * 264 + r] = val;
            }
        }
    }
    // ---- Q fragment (A-operand): row = l15, k = g*8..g*8+7
    int qr = wave * 16 + l15;
    size_t qpix = (size_t)(b * Hh + h0 + (qr >> 3)) * Wd + w0 + (qr & 7);
    bf16x8 aq = *(const bf16x8*)(Q + qpix * Cc + head * HD + g * 8);
    bf16x8 kb;
#pragma unroll
    for (int j = 0; j < 8; ++j) kb[j] = (bf16)bkv[head * HD + g * 8 + j];
    __syncthreads();

    // ---- S = q @ k^T : 16 kv-tiles, K-fragments straight from global
    f32x4 s[16];
#pragma unroll
    for (int t = 0; t < 16; ++t) {
        int r = t * 16 + l15;
        int ph = h0 - OVp + (r >> 4), pw = w0 - OVp + (r & 15);
        bool ok = ((unsigned)ph < (unsigned)Hh) && ((unsigned)pw < (unsigned)Wd);
        size_t pix = ok ? ((size_t)(b * Hh + ph) * Wd + pw) : 0;
        bf16x8 kf = *(const bf16x8*)(KV + pix * (2 * Cc) + head * HD + g * 8);
        kf = ok ? kf : kb;
        f32x4 z = {0.f, 0.f, 0.f, 0.f};
        s[t] = mfma16(aq, kf, z);
    }
    // ---- softmax over kv (rows g*4+rr; 16 lanes of the group share a row-set)
    const float sc = 0.17677669529663689f * 1.4426950408889634f; // scale * log2(e)
#pragma unroll
    for (int rr = 0; rr < 4; ++rr) {
        float m = s[0][rr];
#pragma unroll
        for (int t = 1; t < 16; ++t) m = fmaxf(m, s[t][rr]);
        m = fmaxf(m, __shfl_xor(m, 1)); m = fmaxf(m, __shfl_xor(m, 2));
        m = fmaxf(m, __shfl_xor(m, 4)); m = fmaxf(m, __shfl_xor(m, 8));
        float p[16]; float sum = 0.f;
#pragma unroll
        for (int t = 0; t < 16; ++t) { p[t] = exp2f((s[t][rr] - m) * sc); sum += p[t]; }
        sum += __shfl_xor(sum, 1); sum += __shfl_xor(sum, 2);
        sum += __shfl_xor(sum, 4); sum += __shfl_xor(sum, 8);
        float inv = 1.f / sum;
        int prow = wave * 16 + g * 4 + rr;
#pragma unroll
        for (int t = 0; t < 16; ++t) P[prow * 264 + t * 16 + l15] = (bf16)(p[t] * inv);
    }
    __syncthreads();
    // ---- O = P @ V
    f32x4 o[2] = {};
#pragma unroll
    for (int kk = 0; kk < 8; ++kk) {
        bf16x8 ap = *(const bf16x8*)(&P[(wave * 16 + l15) * 264 + kk * 32 + g * 8]);
#pragma unroll
        for (int nt = 0; nt < 2; ++nt) {
            bf16x8 bv = *(const bf16x8*)(&VT[(nt * 16 + l15) * 264 + kk * 32 + g * 8]);
            o[nt] = mfma16(ap, bv, o[nt]);
        }
    }
#pragma unroll
    for (int nt = 0; nt < 2; ++nt)
#pragma unroll
        for (int r = 0; r < 4; ++r) {
            int row = wave * 16 + g * 4 + r;
            size_t pix = (size_t)(b * Hh + h0 + (row >> 3)) * Wd + w0 + (row & 7);
            O[pix * Cc + head * HD + nt * 16 + l15] = (bf16)o[nt][r];
        }
}

// ---------------------------------------------------------------- K5: O-proj + residual (BHWC->BCHW)
__global__ __launch_bounds__(256) void k_out(const bf16* __restrict__ A,
                                             const bf16* __restrict__ WoT,
                                             const float* __restrict__ bo,
                                             const float* __restrict__ x,
                                             float* __restrict__ out) {
    int row0 = blockIdx.x * 64;
    int tid = threadIdx.x, wave = tid >> 6, lane = tid & 63;
    int l15 = lane & 15, g = lane >> 4;
    int nb = wave * 48;
    f32x4 acc[4][3] = {};
    const bf16* Arow[4];
#pragma unroll
    for (int mt = 0; mt < 4; ++mt) Arow[mt] = A + (size_t)(row0 + mt * 16 + l15) * Cc + g * 8;
    const bf16* Wrow[3];
#pragma unroll
    for (int nt = 0; nt < 3; ++nt) Wrow[nt] = WoT + (size_t)(nb + nt * 16 + l15) * Cc + g * 8;
#pragma unroll
    for (int kk = 0; kk < 6; ++kk) {
        bf16x8 a[4];
#pragma unroll
        for (int mt = 0; mt < 4; ++mt) a[mt] = *(const bf16x8*)(Arow[mt] + kk * 32);
#pragma unroll
        for (int nt = 0; nt < 3; ++nt) {
            bf16x8 bb = *(const bf16x8*)(Wrow[nt] + kk * 32);
#pragma unroll
            for (int mt = 0; mt < 4; ++mt) acc[mt][nt] = mfma16(a[mt], bb, acc[mt][nt]);
        }
    }
    __shared__ float st[192 * 65];
#pragma unroll
    for (int nt = 0; nt < 3; ++nt) {
        float bval = bo[nb + nt * 16 + l15];
#pragma unroll
        for (int mt = 0; mt < 4; ++mt)
#pragma unroll
            for (int r = 0; r < 4; ++r) {
                int ccol = nb + nt * 16 + l15;
                int px = mt * 16 + g * 4 + r;
                st[ccol * 65 + px] = acc[mt][nt][r] + bval;
            }
    }
    __syncthreads();
    int bb2 = row0 / (Hh * Wd);
    int rem = row0 % (Hh * Wd);
    int h = rem / Wd, wstart = rem % Wd;
    for (int idx = tid; idx < 192 * 64; idx += 256) {
        int cc = idx >> 6, px = idx & 63;
        size_t ga = ((size_t)(bb2 * Cc + cc) * Hh + h) * Wd + wstart + px;
        out[ga] = st[cc * 65 + px] + x[ga];
    }
}

// ---------------------------------------------------------------- launch
extern "C" void kernel_launch(void* const* d_in, const int* in_sizes, int n_in,
                              void* d_out, int out_size, void* d_ws, size_t ws_size,
                              hipStream_t stream) {
    const float* x     = (const float*)d_in[0];
    const float* gamma = (const float*)d_in[1];
    const float* beta  = (const float*)d_in[2];
    const float* Wq    = (const float*)d_in[3];
    const float* bq    = (const float*)d_in[4];
    const float* Wkv   = (const float*)d_in[5];
    const float* bkv   = (const float*)d_in[6];
    const float* Wo    = (const float*)d_in[7];
    const float* bo    = (const float*)d_in[8];
    float* out = (float*)d_out;

    char* ws = (char*)d_ws;
    constexpr size_t LN_BYTES = (size_t)Mtot * Cc * 2;      // 100663296
    bf16* ln   = (bf16*)(ws);                                // aliased as attn_out later
    bf16* Qb   = (bf16*)(ws + LN_BYTES);
    bf16* KVb  = (bf16*)(ws + 2 * LN_BYTES);
    bf16* WqT  = (bf16*)(ws + 4 * LN_BYTES);
    bf16* WkvT = (bf16*)(ws + 4 * LN_BYTES + 73728);
    bf16* WoT  = (bf16*)(ws + 4 * LN_BYTES + 73728 + 147456);

    k_prep<<<288, 256, 0, stream>>>(Wq, Wkv, Wo, WqT, WkvT, WoT);
    k_ln<<<Bn * Hh, 256, 0, stream>>>(x, gamma, beta, ln);
    k_gemm<192><<<Mtot / 64, 256, 0, stream>>>(ln, WqT, bq, Qb);
    k_gemm<384><<<Mtot / 64, 256, 0, stream>>>(ln, WkvT, bkv, KVb);
    k_attn<<<4096 * NHd, 256, 0, stream>>>(Qb, KVb, bkv, ln /*attn_out, ln is dead*/);
    k_out<<<Mtot / 64, 256, 0, stream>>>(ln, WoT, bo, x, out);
}

// Round 2
// 749.835 us; speedup vs baseline: 1.3792x; 1.3792x over previous
//
#include <hip/hip_runtime.h>
#include <hip/hip_bf16.h>

typedef __bf16 bf16;
typedef __bf16 bf16x8 __attribute__((ext_vector_type(8)));
typedef float f32x4 __attribute__((ext_vector_type(4)));

#define DEVI static __device__ __forceinline__

static constexpr int Bn = 4, Cc = 192, Hh = 256, Wd = 256;
static constexpr int NHd = 6, HD = 32;
static constexpr int Mtot = Bn * Hh * Wd;          // 262144 pixels
static constexpr float EPSv = 1e-5f;

DEVI f32x4 mfma16(bf16x8 a, bf16x8 b, f32x4 c) {
    return __builtin_amdgcn_mfma_f32_16x16x32_bf16(a, b, c, 0, 0, 0);
}

// ---------------------------------------------------------------- K0: weights
// WT576[n][k]: rows 0..191 = Wq^T, rows 192..575 = Wkv^T.  WoT[n][k] = Wo^T.
__global__ __launch_bounds__(256) void k_prep(const float* Wq, const float* Wkv,
                                              const float* Wo, bf16* WT, bf16* WoT) {
    int idx = blockIdx.x * 256 + threadIdx.x;
    if (idx < 576 * 192) {
        int n = idx / 192, k = idx % 192;
        float v = (n < 192) ? Wq[k * 192 + n] : Wkv[k * 384 + (n - 192)];
        WT[idx] = (bf16)v;
    } else if (idx < 576 * 192 + 192 * 192) {
        int j = idx - 576 * 192;
        int n = j / 192, k = j % 192;
        WoT[j] = (bf16)Wo[k * 192 + n];
    }
}

// ---------------------------------------------------------------- K1: fused LN + QKV projection
// Block = 64 consecutive pixels (same b,h row). LN stats via register pass +
// LDS cross-wave reduce; A-tile (bf16) in LDS; one 64x576 GEMM.
// Q -> [pix][192]; K,V -> head-major [head][pix][32].
__global__ __launch_bounds__(256) void k_lnqkv(const float* __restrict__ x,
                                               const float* __restrict__ gamma,
                                               const float* __restrict__ beta,
                                               const bf16* __restrict__ WT,
                                               const float* __restrict__ bq,
                                               const float* __restrict__ bkv,
                                               bf16* __restrict__ Q,
                                               bf16* __restrict__ K,
                                               bf16* __restrict__ V) {
    constexpr int AS = 200;                       // A-tile LDS stride (elements)
    __shared__ __align__(16) bf16 A[64 * AS];
    __shared__ float red[2][4][64];
    __shared__ float sg[Cc], sbv[Cc];

    int tid = threadIdx.x;
    int q = tid >> 6, p = tid & 63;
    int base = blockIdx.x * 64;
    int b = base >> 16;
    int hw = base & 65535;
    int h = hw >> 8, w0 = hw & 255;
    if (tid < Cc) { sg[tid] = gamma[tid]; sbv[tid] = beta[tid]; }

    // pass over 48 channels per wave, x in registers
    const float* xb = x + ((size_t)(b * Cc + q * 48) * Hh + h) * Wd + w0 + p;
    float xv[48];
    float s = 0.f, s2 = 0.f;
#pragma unroll
    for (int i = 0; i < 48; ++i) {
        float v = xb[(size_t)i * Hh * Wd];
        xv[i] = v; s += v; s2 += v * v;
    }
    red[0][q][p] = s; red[1][q][p] = s2;
    __syncthreads();
    float mu = (red[0][0][p] + red[0][1][p] + red[0][2][p] + red[0][3][p]) * (1.f / 192.f);
    float m2 = (red[1][0][p] + red[1][1][p] + red[1][2][p] + red[1][3][p]) * (1.f / 192.f);
    float rs = rsqrtf(m2 - mu * mu + EPSv);
#pragma unroll
    for (int i0 = 0; i0 < 48; i0 += 8) {
        bf16x8 o;
#pragma unroll
        for (int j = 0; j < 8; ++j) {
            int c = q * 48 + i0 + j;
            o[j] = (bf16)((xv[i0 + j] - mu) * rs * sg[c] + sbv[c]);
        }
        *(bf16x8*)&A[p * AS + q * 48 + i0] = o;
    }
    __syncthreads();

    // GEMM: 4 waves x 144 output cols
    int lane = tid & 63, l15 = lane & 15, g = lane >> 4;
    int wave = q;
    f32x4 acc[4][9] = {};
    const bf16* Wbase = WT + (size_t)(wave * 144 + l15) * Cc + g * 8;
#pragma unroll
    for (int kk = 0; kk < 6; ++kk) {
        bf16x8 a[4];
#pragma unroll
        for (int mt = 0; mt < 4; ++mt)
            a[mt] = *(bf16x8*)&A[(mt * 16 + l15) * AS + kk * 32 + g * 8];
#pragma unroll
        for (int nt = 0; nt < 9; ++nt) {
            bf16x8 bb = *(const bf16x8*)(Wbase + (size_t)nt * 16 * Cc + kk * 32);
#pragma unroll
            for (int mt = 0; mt < 4; ++mt) acc[mt][nt] = mfma16(a[mt], bb, acc[mt][nt]);
        }
    }
#pragma unroll
    for (int nt = 0; nt < 9; ++nt) {
        int n = wave * 144 + nt * 16 + l15;
        float bval = (n < 192) ? bq[n] : bkv[n - 192];
#pragma unroll
        for (int mt = 0; mt < 4; ++mt)
#pragma unroll
            for (int r = 0; r < 4; ++r) {
                int pix = base + mt * 16 + g * 4 + r;
                bf16 val = (bf16)(acc[mt][nt][r] + bval);
                if (n < 192)
                    Q[(size_t)pix * Cc + n] = val;
                else if (n < 384)
                    K[((size_t)((n - 192) >> 5) * Mtot + pix) * HD + ((n - 192) & 31)] = val;
                else
                    V[((size_t)((n - 384) >> 5) * Mtot + pix) * HD + ((n - 384) & 31)] = val;
            }
    }
}

// ---------------------------------------------------------------- K2: attention
// One block per (head, window); 4 waves x 16 q-rows; kv = 256 overlapping rows.
// K/V head-major -> coalesced 1KB gathers; interior windows skip all masking.
__global__ __launch_bounds__(256) void k_attn(const bf16* __restrict__ Q,
                                              const bf16* __restrict__ K,
                                              const bf16* __restrict__ V,
                                              const float* __restrict__ bkv,
                                              bf16* __restrict__ O) {
    int bid = blockIdx.x;
    bid = (bid & 7) * 3072 + (bid >> 3);          // chunked XCD swizzle (24576 = 8*3072)
    int head = bid >> 12;                          // /4096
    int win = bid & 4095;
    int b = win >> 10, wloc = win & 1023;
    int h0 = ((wloc >> 5) << 3), w0 = ((wloc & 31) << 3);
    bool interior = (h0 != 0) && (h0 != Hh - 8) && (w0 != 0) && (w0 != Wd - 8);

    int tid = threadIdx.x, wave = tid >> 6, lane = tid & 63;
    int l15 = lane & 15, g = lane >> 4;

    const bf16* Kh = K + (size_t)head * Mtot * HD;
    const bf16* Vh = V + (size_t)head * Mtot * HD;
    long long p00 = (long long)(b * Hh + h0 - 4) * Wd + (w0 - 4);

    __shared__ __align__(16) bf16 VT[32 * 264];   // V^T [d][kv]
    __shared__ __align__(16) bf16 P[64 * 264];    // probs [qrow][kv] (unnormalized)

    // ---- stage V^T (one kv row per thread)
    if (interior) {
        int r = tid;
        const bf16* vr = Vh + (p00 + (r >> 4) * Wd + (r & 15)) * HD;
#pragma unroll
        for (int d0 = 0; d0 < 32; d0 += 8) {
            bf16x8 v8 = *(const bf16x8*)(vr + d0);
#pragma unroll
            for (int j = 0; j < 8; ++j) VT[(d0 + j) * 264 + r] = v8[j];
        }
    } else {
        int r = tid;
        int ph = h0 - 4 + (r >> 4), pw = w0 - 4 + (r & 15);
        bool ok = ((unsigned)ph < (unsigned)Hh) && ((unsigned)pw < (unsigned)Wd);
        long long pix = ok ? ((long long)(b * Hh + ph) * Wd + pw) : 0;
        const bf16* vr = Vh + pix * HD;
        const float* vb = bkv + Cc + head * HD;
#pragma unroll
        for (int d0 = 0; d0 < 32; d0 += 8) {
            bf16x8 v8 = *(const bf16x8*)(vr + d0);
#pragma unroll
            for (int j = 0; j < 8; ++j) VT[(d0 + j) * 264 + r] = ok ? v8[j] : (bf16)vb[d0 + j];
        }
    }

    // ---- Q fragment
    int qr = wave * 16 + l15;
    size_t qpix = (size_t)(b * Hh + h0 + (qr >> 3)) * Wd + w0 + (qr & 7);
    bf16x8 aq = *(const bf16x8*)(Q + qpix * Cc + head * HD + g * 8);
    bf16x8 kb;
#pragma unroll
    for (int j = 0; j < 8; ++j) kb[j] = (bf16)bkv[head * HD + g * 8 + j];
    __syncthreads();

    // ---- S = q @ k^T : 16 kv-tiles
    f32x4 s[16];
    const f32x4 z = {0.f, 0.f, 0.f, 0.f};
    const bf16* kp = Kh + (p00 + l15) * HD + g * 8;
    if (interior) {
#pragma unroll
        for (int t = 0; t < 16; ++t) {
            bf16x8 kf = *(const bf16x8*)(kp + (size_t)t * Wd * HD);
            s[t] = mfma16(aq, kf, z);
        }
    } else {
        bool colok = ((unsigned)(w0 - 4 + l15) < (unsigned)Wd);
#pragma unroll
        for (int t = 0; t < 16; ++t) {
            int ph = h0 - 4 + t;                  // wave-uniform
            bf16x8 kf;
            if ((unsigned)ph < (unsigned)Hh) {
                kf = *(const bf16x8*)(kp + (size_t)t * Wd * HD);
                kf = colok ? kf : kb;
            } else {
                kf = kb;
            }
            s[t] = mfma16(aq, kf, z);
        }
    }

    // ---- softmax over kv (deferred normalization)
    const float sc = 0.17677669529663689f * 1.4426950408889634f; // scale * log2(e)
    float inv[4];
#pragma unroll
    for (int rr = 0; rr < 4; ++rr) {
        float m = s[0][rr];
#pragma unroll
        for (int t = 1; t < 16; ++t) m = fmaxf(m, s[t][rr]);
        m = fmaxf(m, __shfl_xor(m, 1)); m = fmaxf(m, __shfl_xor(m, 2));
        m = fmaxf(m, __shfl_xor(m, 4)); m = fmaxf(m, __shfl_xor(m, 8));
        float pv[16]; float sum = 0.f;
#pragma unroll
        for (int t = 0; t < 16; ++t) {
            pv[t] = __builtin_amdgcn_exp2f((s[t][rr] - m) * sc);
            sum += pv[t];
        }
        sum += __shfl_xor(sum, 1); sum += __shfl_xor(sum, 2);
        sum += __shfl_xor(sum, 4); sum += __shfl_xor(sum, 8);
        inv[rr] = __builtin_amdgcn_rcpf(sum);
        int prow = wave * 16 + g * 4 + rr;
#pragma unroll
        for (int t = 0; t < 16; ++t) P[prow * 264 + t * 16 + l15] = (bf16)pv[t];
    }
    __builtin_amdgcn_wave_barrier();   // P rows are wave-private; ordering only

    // ---- O = P @ V (normalize at epilogue)
    f32x4 o[2] = {};
#pragma unroll
    for (int kk = 0; kk < 8; ++kk) {
        bf16x8 ap = *(const bf16x8*)(&P[(wave * 16 + l15) * 264 + kk * 32 + g * 8]);
#pragma unroll
        for (int nt = 0; nt < 2; ++nt) {
            bf16x8 bv = *(const bf16x8*)(&VT[(nt * 16 + l15) * 264 + kk * 32 + g * 8]);
            o[nt] = mfma16(ap, bv, o[nt]);
        }
    }
#pragma unroll
    for (int nt = 0; nt < 2; ++nt)
#pragma unroll
        for (int r = 0; r < 4; ++r) {
            int row = wave * 16 + g * 4 + r;
            size_t pix = (size_t)(b * Hh + h0 + (row >> 3)) * Wd + w0 + (row & 7);
            O[pix * Cc + head * HD + nt * 16 + l15] = (bf16)(o[nt][r] * inv[r]);
        }
}

// ---------------------------------------------------------------- K3: O-proj + residual (BHWC->BCHW)
__global__ __launch_bounds__(256) void k_out(const bf16* __restrict__ A,
                                             const bf16* __restrict__ WoT,
                                             const float* __restrict__ bo,
                                             const float* __restrict__ x,
                                             float* __restrict__ out) {
    int row0 = blockIdx.x * 64;
    int tid = threadIdx.x, wave = tid >> 6, lane = tid & 63;
    int l15 = lane & 15, g = lane >> 4;
    int nb = wave * 48;
    f32x4 acc[4][3] = {};
    const bf16* Arow[4];
#pragma unroll
    for (int mt = 0; mt < 4; ++mt) Arow[mt] = A + (size_t)(row0 + mt * 16 + l15) * Cc + g * 8;
    const bf16* Wrow[3];
#pragma unroll
    for (int nt = 0; nt < 3; ++nt) Wrow[nt] = WoT + (size_t)(nb + nt * 16 + l15) * Cc + g * 8;
#pragma unroll
    for (int kk = 0; kk < 6; ++kk) {
        bf16x8 a[4];
#pragma unroll
        for (int mt = 0; mt < 4; ++mt) a[mt] = *(const bf16x8*)(Arow[mt] + kk * 32);
#pragma unroll
        for (int nt = 0; nt < 3; ++nt) {
            bf16x8 bb = *(const bf16x8*)(Wrow[nt] + kk * 32);
#pragma unroll
            for (int mt = 0; mt < 4; ++mt) acc[mt][nt] = mfma16(a[mt], bb, acc[mt][nt]);
        }
    }
    __shared__ float st[192 * 65];
#pragma unroll
    for (int nt = 0; nt < 3; ++nt) {
        float bval = bo[nb + nt * 16 + l15];
#pragma unroll
        for (int mt = 0; mt < 4; ++mt)
#pragma unroll
            for (int r = 0; r < 4; ++r) {
                int ccol = nb + nt * 16 + l15;
                int px = mt * 16 + g * 4 + r;
                st[ccol * 65 + px] = acc[mt][nt][r] + bval;
            }
    }
    __syncthreads();
    int bb2 = row0 / (Hh * Wd);
    int rem = row0 % (Hh * Wd);
    int h = rem / Wd, wstart = rem % Wd;
    for (int idx = tid; idx < 192 * 64; idx += 256) {
        int cc = idx >> 6, px = idx & 63;
        size_t ga = ((size_t)(bb2 * Cc + cc) * Hh + h) * Wd + wstart + px;
        out[ga] = st[cc * 65 + px] + x[ga];
    }
}

// ---------------------------------------------------------------- launch
extern "C" void kernel_launch(void* const* d_in, const int* in_sizes, int n_in,
                              void* d_out, int out_size, void* d_ws, size_t ws_size,
                              hipStream_t stream) {
    const float* x     = (const float*)d_in[0];
    const float* gamma = (const float*)d_in[1];
    const float* beta  = (const float*)d_in[2];
    const float* Wq    = (const float*)d_in[3];
    const float* bq    = (const float*)d_in[4];
    const float* Wkv   = (const float*)d_in[5];
    const float* bkv   = (const float*)d_in[6];
    const float* Wo    = (const float*)d_in[7];
    const float* bo    = (const float*)d_in[8];
    float* out = (float*)d_out;

    char* ws = (char*)d_ws;
    constexpr size_t SEG = (size_t)Mtot * Cc * 2;          // 100663296 B
    bf16* Qb  = (bf16*)(ws);
    bf16* Kb  = (bf16*)(ws + SEG);                          // head-major, 6*Mtot*32
    bf16* Vb  = (bf16*)(ws + 2 * SEG);
    bf16* AO  = (bf16*)(ws + 3 * SEG);
    bf16* WT  = (bf16*)(ws + 4 * SEG);                      // 576*192*2 = 221184
    bf16* WoT = (bf16*)(ws + 4 * SEG + 221184);             // 192*192*2 = 73728

    k_prep<<<576, 256, 0, stream>>>(Wq, Wkv, Wo, WT, WoT);
    k_lnqkv<<<Mtot / 64, 256, 0, stream>>>(x, gamma, beta, WT, bq, bkv, Qb, Kb, Vb);
    k_attn<<<4096 * NHd, 256, 0, stream>>>(Qb, Kb, Vb, bkv, AO);
    k_out<<<Mtot / 64, 256, 0, stream>>>(AO, WoT, bo, x, out);
}